// Round 1
// baseline (133.051 us; speedup 1.0000x reference)
//
#include <hip/hip_runtime.h>

#define NREPS   16
#define NELEMS  128
#define NSYM    64
#define DD      32
#define MATSZ   (DD * DD)        // 1024 floats per 32x32 block
#define EMB     (NREPS * MATSZ)  // 16384

// ---------------- Kernel 1: inverse Frobenius scale per (r,e) ----------------
// grid = 2048 blocks (one per matrix), block = 256 threads.
__global__ __launch_bounds__(256) void fro_kernel(const float* __restrict__ reps,
                                                  float* __restrict__ inv) {
    const int mat = blockIdx.x;            // r*128 + e
    const int t   = threadIdx.x;           // 0..255, 4 floats each
    float4 v = reinterpret_cast<const float4*>(reps + (size_t)mat * MATSZ)[t];
    float s = v.x * v.x + v.y * v.y + v.z * v.z + v.w * v.w;
    #pragma unroll
    for (int off = 32; off > 0; off >>= 1)
        s += __shfl_down(s, off, 64);
    __shared__ float red[4];
    if ((t & 63) == 0) red[t >> 6] = s;
    __syncthreads();
    if (t == 0) {
        float tot = red[0] + red[1] + red[2] + red[3];
        inv[mat] = 1.0f / (sqrtf(tot) + 1e-6f);
    }
}

// ---------------- Kernel 2: out[b,r] = A[b,r] (32x32) @ Mn[r, e(b)] ----------
// block = 128 threads (2 waves); one block covers batch b, reps [half*8, half*8+8).
// Wave = 4 reps (lane groups of 16); each lane computes an 8x8 output block.
// A is LDS-staged with an XOR swizzle so strided row reads are conflict-free.
// M rows come straight from global (L1/L2-resident, 4KB per matrix).
__global__ __launch_bounds__(128) void trans_kernel(
    const float* __restrict__ emb,     // [B][16384]
    const int*   __restrict__ syms,    // [B]
    const float* __restrict__ reps,    // [16][128][32][32]
    const int*   __restrict__ trans,   // [64]
    const float* __restrict__ inv,     // [2048]
    float*       __restrict__ out)     // [B][16384]
{
    __shared__ float lA[8 * MATSZ];    // 32 KiB, swizzled
    const int b    = blockIdx.x >> 1;
    const int half = blockIdx.x & 1;
    const int t    = threadIdx.x;      // 0..127

    const float* Ab = emb + (size_t)b * EMB + (size_t)half * (8 * MATSZ);

    // ---- stage 8 rep-blocks (8192 floats) into LDS, swizzled ----
    #pragma unroll
    for (int it = 0; it < 16; ++it) {
        const int chunk = it * 128 + t;            // float4 index 0..2047
        float4 v = reinterpret_cast<const float4*>(Ab)[chunk];
        const int e  = chunk << 2;
        const int rl = e >> 10;                    // local rep 0..7
        const int i  = (e >> 5) & 31;              // row
        const int k0 = e & 31;                     // col base (multiple of 4)
        const int m3 = ((i >> 3) & 3) | ((rl & 1) << 2);
        const int koff = ((k0 >> 2) ^ m3) << 2;
        *reinterpret_cast<float4*>(&lA[rl * MATSZ + i * 32 + koff]) = v;
    }
    __syncthreads();

    const int w  = t >> 6;                  // wave 0..1
    const int l  = t & 63;
    const int g  = l >> 4;                  // rep group within wave 0..3
    const int rl = w * 4 + g;               // local rep 0..7
    const int r  = half * 8 + rl;           // global rep 0..15
    const int ll = l & 15;
    const int i0 = (ll >> 2) << 3;          // {0,8,16,24}
    const int j0 = (ll & 3) << 3;           // {0,8,16,24}

    const int esym = trans[syms[b]];        // group element for this batch
    const float* M = reps + ((size_t)r * NELEMS + esym) * MATSZ;
    const float scale = inv[r * NELEMS + esym];

    float acc[8][8];
    #pragma unroll
    for (int m = 0; m < 8; ++m)
        #pragma unroll
        for (int j = 0; j < 8; ++j) acc[m][j] = 0.0f;

    const int m3r = ((i0 >> 3) & 3) | ((rl & 1) << 2);
    const float* lab = &lA[rl * MATSZ + i0 * 32];

    #pragma unroll
    for (int kb = 0; kb < 8; ++kb) {        // contraction in blocks of 4
        const int koff = ((kb ^ m3r) << 2);
        float4 a[8];
        #pragma unroll
        for (int m = 0; m < 8; ++m)
            a[m] = *reinterpret_cast<const float4*>(lab + m * 32 + koff);

        float4 mv[4][2];
        #pragma unroll
        for (int kk = 0; kk < 4; ++kk) {
            const float* Mr = M + (kb * 4 + kk) * 32 + j0;
            mv[kk][0] = *reinterpret_cast<const float4*>(Mr);
            mv[kk][1] = *reinterpret_cast<const float4*>(Mr + 4);
        }

        #pragma unroll
        for (int kk = 0; kk < 4; ++kk) {
            #pragma unroll
            for (int m = 0; m < 8; ++m) {
                const float av = (&a[m].x)[kk];   // kk is compile-time (unrolled)
                acc[m][0] += av * mv[kk][0].x;
                acc[m][1] += av * mv[kk][0].y;
                acc[m][2] += av * mv[kk][0].z;
                acc[m][3] += av * mv[kk][0].w;
                acc[m][4] += av * mv[kk][1].x;
                acc[m][5] += av * mv[kk][1].y;
                acc[m][6] += av * mv[kk][1].z;
                acc[m][7] += av * mv[kk][1].w;
            }
        }
    }

    // ---- epilogue: apply Frobenius scale, store 8x8 block ----
    float* Ob = out + (size_t)b * EMB + (size_t)r * MATSZ + i0 * 32 + j0;
    #pragma unroll
    for (int m = 0; m < 8; ++m) {
        float4 o0 = make_float4(acc[m][0] * scale, acc[m][1] * scale,
                                acc[m][2] * scale, acc[m][3] * scale);
        float4 o1 = make_float4(acc[m][4] * scale, acc[m][5] * scale,
                                acc[m][6] * scale, acc[m][7] * scale);
        *reinterpret_cast<float4*>(Ob + m * 32)     = o0;
        *reinterpret_cast<float4*>(Ob + m * 32 + 4) = o1;
    }
}

extern "C" void kernel_launch(void* const* d_in, const int* in_sizes, int n_in,
                              void* d_out, int out_size, void* d_ws, size_t ws_size,
                              hipStream_t stream) {
    const float* emb   = (const float*)d_in[0];
    const int*   syms  = (const int*)d_in[1];
    const float* reps  = (const float*)d_in[2];
    const int*   trans = (const int*)d_in[3];
    float* outp = (float*)d_out;
    float* inv  = (float*)d_ws;          // 2048 floats = 8 KB scratch

    const int B = in_sizes[1];           // batch count (4096)

    hipLaunchKernelGGL(fro_kernel, dim3(NREPS * NELEMS), dim3(256), 0, stream,
                       reps, inv);
    hipLaunchKernelGGL(trans_kernel, dim3(B * 2), dim3(128), 0, stream,
                       emb, syms, reps, trans, inv, outp);
}